// Round 4
// baseline (630.428 us; speedup 1.0000x reference)
//
#include <hip/hip_runtime.h>

#define NN 8
#define HH 12
#define DH 64
#define LV 1568
#define LA 512
#define NCV 392
#define NCA 256
#define SCALE 0.125f
#define NTOK (NCV + NCA)                                 // 648 selected tokens per n

#define OUT_STRIDE (LV + LA + 2 * HH * DH + LV + LA)   // 5696
#define OFF_PROB_V 0
#define OFF_PROB_A (LV)                                 // 1568
#define OFF_VCLS   (LV + LA)                            // 2080
#define OFF_ACLS   (LV + LA + HH * DH)                  // 2848
#define OFF_PR_AV  (LV + LA + 2 * HH * DH)              // 3616
#define OFF_PR_VA  (LV + LA + 2 * HH * DH + LV)         // 5184

#define CH 4    // row-chunks: av 256/4 = 64 rows/chunk, va 392/4 = 98 rows/chunk

// workspace layout (float offsets) — per-chunk PARTIALS + spu dots, no atomics
#define WS_RV      0                                     // [CH][N*H][LV] = 602112
#define WS_RA      (CH * NN * HH * LV)                   // [CH][N*H][LA] = 196608
#define WS_SPU     (WS_RA + CH * NN * HH * LA)           // [N*NTOK][HH]  = 62208
#define WS_INV_SAV (WS_SPU + NN * NTOK * HH)
#define WS_INV_SVA (WS_INV_SAV + NN)

// stage-1 block ranges (longest/BW-bound first so they start immediately)
#define B_RAV   (NN * HH * CH)                           // 384 av-rowsum blocks
#define B_RVA   (NN * HH * CH)                           // 384 va-rowsum blocks
#define B_SPU   (NN * NTOK / 4)                          // 1296 spu-dot blocks (4 waves ea)
#define B_CLS   (2 * NN * HH)                            // 192 cls blocks
#define B_INV   NN                                       // 8 inv-sum blocks
#define TAILV   (NN * (LV - NCV))                        // 9408
#define TAILA   (NN * (LA - NCA))                        // 2048
#define B_TAIL  ((TAILV + TAILA + 255) / 256)            // 45 dense-tail blocks
#define GRID_S1 (B_RAV + B_RVA + B_SPU + B_CLS + B_INV + B_TAIL)   // 2309

// ---------------------------------------------------------------------------
// stage1: rowsum partials + spu dot-products + cls + inv-sums + dense tail.
// Everything not depending on the rowsum partials lives here so the latency-
// bound gathers hide under the rowsum bandwidth stream.
// ---------------------------------------------------------------------------
__global__ __launch_bounds__(256) void stage1_kernel(
        const float* __restrict__ pvq,
        const float* __restrict__ paq,
        const float* __restrict__ pvk,
        const float* __restrict__ pak,
        const float* __restrict__ av,    // (N,H,LA,LV)
        const float* __restrict__ va,    // (N,H,LV,LA)
        const float* __restrict__ spu_a, // (N,H,DH)
        const float* __restrict__ spu_v,
        const int* __restrict__ av_ids,
        const int* __restrict__ va_ids,
        const float* __restrict__ n_av,
        const float* __restrict__ n_va,
        float* __restrict__ ws,
        float* __restrict__ out) {
    int b = blockIdx.x;
    int t = threadIdx.x;
    __shared__ float red[4][DH];
    __shared__ float wred[4];
    __shared__ int   sIdx[128];
    __shared__ float sW[128];

    if (b < B_RAV) {
        // ---- av rowsum partial: sum over 64 selected rows ----
        int chunk = b % CH;
        int nh    = b / CH;
        int n     = nh / HH;
        const int rows = NCA / CH;         // 64
        for (int r = t; r < rows; r += 256) {
            int ridx = va_ids[n * LA + chunk * rows + r];
            sIdx[r] = ridx;
            sW[r]   = n_va[n * LA + ridx];
        }
        __syncthreads();
        float4 acc0 = {0.f, 0.f, 0.f, 0.f};
        float4 acc1 = {0.f, 0.f, 0.f, 0.f};
        const int c0 = t;                  // float4 column
        const int c1 = t + 256;
        const bool has1 = (c1 < LV / 4);   // LV/4 = 392
        #pragma unroll 4
        for (int r = 0; r < rows; ++r) {
            float w = sW[r];
            const float4* row = (const float4*)(av + ((size_t)nh * LA + sIdx[r]) * LV);
            float4 x0 = row[c0];
            acc0.x += x0.x * w; acc0.y += x0.y * w; acc0.z += x0.z * w; acc0.w += x0.w * w;
            if (has1) {
                float4 x1 = row[c1];
                acc1.x += x1.x * w; acc1.y += x1.y * w; acc1.z += x1.z * w; acc1.w += x1.w * w;
            }
        }
        float4* outp = (float4*)(ws + WS_RV + ((size_t)chunk * NN * HH + nh) * LV);
        outp[c0] = acc0;
        if (has1) outp[c1] = acc1;
        return;
    }
    b -= B_RAV;

    if (b < B_RVA) {
        // ---- va rowsum partial: sum over 98 selected rows ----
        int chunk = b % CH;
        int nh    = b / CH;
        int n     = nh / HH;
        const int rows = NCV / CH;         // 98
        for (int r = t; r < rows; r += 256) {
            int ridx = av_ids[n * LV + chunk * rows + r];
            sIdx[r] = ridx;
            sW[r]   = n_av[n * LV + ridx];
        }
        __syncthreads();
        float2 acc = {0.f, 0.f};
        #pragma unroll 4
        for (int r = 0; r < rows; ++r) {
            float w = sW[r];
            const float2* row = (const float2*)(va + ((size_t)nh * LV + sIdx[r]) * LA);
            float2 x = row[t];             // LA/2 = 256 exactly
            acc.x += x.x * w; acc.y += x.y * w;
        }
        ((float2*)(ws + WS_RA + ((size_t)chunk * NN * HH + nh) * LA))[t] = acc;
        return;
    }
    b -= B_RVA;

    if (b < B_SPU) {
        // ---- spu dot-products: one wave per selected token, 12 head-dots ----
        int W = b * 4 + (t >> 6);          // global token id 0..5183
        int lane = t & 63;
        int n = W / NTOK, lc = W % NTOK;
        if (lc < NCV) {
            int col = av_ids[n * LV + lc];
            #pragma unroll
            for (int h = 0; h < HH; ++h) {
                int nh = n * HH + h;
                float prod = pvk[((size_t)nh * LV + col) * DH + lane] * spu_a[nh * DH + lane];
                for (int m = 32; m; m >>= 1) prod += __shfl_xor(prod, m);
                if (lane == 0) ws[WS_SPU + (size_t)W * HH + h] = prod * SCALE;
            }
        } else {
            int l = lc - NCV;
            int col = va_ids[n * LA + l];
            #pragma unroll
            for (int h = 0; h < HH; ++h) {
                int nh = n * HH + h;
                float prod = pak[((size_t)nh * LA + col) * DH + lane] * spu_v[nh * DH + lane];
                for (int m = 32; m; m >>= 1) prod += __shfl_xor(prod, m);
                if (lane == 0) ws[WS_SPU + (size_t)W * HH + h] = prod * SCALE;
            }
        }
        return;
    }
    b -= B_SPU;

    if (b < B_CLS) {
        // ---- class tokens ----
        int wave = t >> 6, lane = t & 63;
        if (b < NN * HH) {
            int n = b / HH, h = b % HH;
            float acc = 0.f, wsum = 0.f;
            for (int l = wave; l < NCV; l += 4) {
                int ridx = av_ids[n * LV + l];
                float w  = n_av[n * LV + ridx];
                acc  += pvq[((size_t)b * LV + ridx) * DH + lane] * w;
                wsum += w;
            }
            red[wave][lane] = acc;
            if (lane == 0) wred[wave] = wsum;
            __syncthreads();
            if (wave == 0) {
                float s = red[0][lane] + red[1][lane] + red[2][lane] + red[3][lane];
                float W = wred[0] + wred[1] + wred[2] + wred[3];
                out[(size_t)n * OUT_STRIDE + OFF_VCLS + h * DH + lane] = s / W;
            }
        } else {
            int b2 = b - NN * HH;
            int n = b2 / HH, h = b2 % HH;
            float acc = 0.f, wsum = 0.f;
            for (int l = wave; l < NCA; l += 4) {
                int ridx = va_ids[n * LA + l];
                float w  = n_va[n * LA + ridx];
                acc  += paq[((size_t)b2 * LA + ridx) * DH + lane] * w;
                wsum += w;
            }
            red[wave][lane] = acc;
            if (lane == 0) wred[wave] = wsum;
            __syncthreads();
            if (wave == 0) {
                float s = red[0][lane] + red[1][lane] + red[2][lane] + red[3][lane];
                float W = wred[0] + wred[1] + wred[2] + wred[3];
                out[(size_t)n * OUT_STRIDE + OFF_ACLS + h * DH + lane] = s / W;
            }
        }
        return;
    }
    b -= B_CLS;

    if (b < B_INV) {
        // ---- inverse sums of gathered n_attn ----
        int n = b;
        float vs = 0.f, as = 0.f;
        for (int l = t; l < NCV; l += 256) vs += n_av[n * LV + av_ids[n * LV + l]];
        if (t < NCA) as = n_va[n * LA + va_ids[n * LA + t]];
        for (int m = 32; m; m >>= 1) { vs += __shfl_xor(vs, m); as += __shfl_xor(as, m); }
        int wave = t >> 6;
        if ((t & 63) == 0) { red[wave][0] = vs; wred[wave] = as; }
        __syncthreads();
        if (t == 0) {
            float S0 = red[0][0] + red[1][0] + red[2][0] + red[3][0];
            float S1 = wred[0] + wred[1] + wred[2] + wred[3];
            ws[WS_INV_SAV + n] = 1.f / S0;
            ws[WS_INV_SVA + n] = 1.f / S1;
        }
        return;
    }
    b -= B_INV;

    {
        // ---- dense tail: prob = 0 -> prune = n_attn passthrough ----
        int tid = b * 256 + t;
        if (tid < TAILV) {
            int n = tid / (LV - NCV), l = NCV + tid % (LV - NCV);
            int col = av_ids[n * LV + l];
            out[(size_t)n * OUT_STRIDE + OFF_PROB_V + col] = 0.f;
            out[(size_t)n * OUT_STRIDE + OFF_PR_AV + col] = n_av[n * LV + col];
        } else if (tid < TAILV + TAILA) {
            int i = tid - TAILV;
            int n = i / (LA - NCA), l = NCA + i % (LA - NCA);
            int col = va_ids[n * LA + l];
            out[(size_t)n * OUT_STRIDE + OFF_PROB_A + col] = 0.f;
            out[(size_t)n * OUT_STRIDE + OFF_PR_VA + col] = n_va[n * LA + col];
        }
    }
}

// ---------------------------------------------------------------------------
// prob2: one wave per selected token. Lane (h=lane>>2, p=lane&3), lane<48,
// loads one rowsum partial; fold p via 2 shfl_xor; 12 sigmoid lanes; fold h
// via 4 shfl_xor; lane 0 scatters prob + prune.
// ---------------------------------------------------------------------------
#define GRID_PB (NN * NTOK / 4)                          // 1296 blocks

__global__ __launch_bounds__(256) void prob2_kernel(
        const int* __restrict__ av_ids,
        const int* __restrict__ va_ids,
        const float* __restrict__ n_av,
        const float* __restrict__ n_va,
        const float* __restrict__ u_v,
        const float* __restrict__ u_a,
        const float* __restrict__ ws,
        float* __restrict__ out) {
    int W = blockIdx.x * 4 + (threadIdx.x >> 6);         // token id 0..5183
    int lane = threadIdx.x & 63;
    int n = W / NTOK, lc = W % NTOK;
    bool isV = (lc < NCV);
    int h = lane >> 2, p = lane & 3;                     // valid for lane < 48

    int col;
    float invS, part = 0.f;
    if (isV) {
        col  = av_ids[n * LV + lc];
        invS = ws[WS_INV_SVA + n];
        if (lane < 48)
            part = ws[WS_RV + ((size_t)p * NN * HH + n * HH + h) * LV + col];
    } else {
        col  = va_ids[n * LA + (lc - NCV)];
        invS = ws[WS_INV_SAV + n];
        if (lane < 48)
            part = ws[WS_RA + ((size_t)p * NN * HH + n * HH + h) * LA + col];
    }
    // fold the 4 chunk-partials within each 4-lane group
    part += __shfl_xor(part, 1);
    part += __shfl_xor(part, 2);

    float sig = 0.f;
    if (lane < 48 && (lane & 3) == 0) {
        float spu = ws[WS_SPU + (size_t)W * HH + h];     // already * SCALE
        sig = 1.f / (1.f + __expf(part * invS - spu));
    }
    // fold the 12 head-sigmoids (value lanes 0,4,...,44; lanes 48..60 add 0)
    sig += __shfl_xor(sig, 4);
    sig += __shfl_xor(sig, 8);
    sig += __shfl_xor(sig, 16);
    sig += __shfl_xor(sig, 32);

    if (lane == 0) {
        float pm = sig * (1.f / HH);
        if (isV) {
            out[(size_t)n * OUT_STRIDE + OFF_PROB_V + col] = pm;
            float uv = u_v[n * LV + col];
            out[(size_t)n * OUT_STRIDE + OFF_PR_AV + col] =
                (uv < pm) ? 0.f : n_av[n * LV + col];
        } else {
            out[(size_t)n * OUT_STRIDE + OFF_PROB_A + col] = pm;
            float ua = u_a[n * LA + col];
            out[(size_t)n * OUT_STRIDE + OFF_PR_VA + col] =
                (ua < pm) ? 0.f : n_va[n * LA + col];
        }
    }
}

extern "C" void kernel_launch(void* const* d_in, const int* in_sizes, int n_in,
                              void* d_out, int out_size, void* d_ws, size_t ws_size,
                              hipStream_t stream) {
    const float* pvq   = (const float*)d_in[0];
    const float* pvk   = (const float*)d_in[1];
    const float* paq   = (const float*)d_in[2];
    const float* pak   = (const float*)d_in[3];
    const float* av    = (const float*)d_in[4];
    const float* va    = (const float*)d_in[5];
    const float* n_av  = (const float*)d_in[6];
    const float* n_va  = (const float*)d_in[7];
    const float* spu_a = (const float*)d_in[8];
    const float* spu_v = (const float*)d_in[9];
    const float* u_v   = (const float*)d_in[10];
    const float* u_a   = (const float*)d_in[11];
    const int* av_ids  = (const int*)d_in[12];
    const int* va_ids  = (const int*)d_in[13];
    float* out = (float*)d_out;
    float* ws  = (float*)d_ws;

    stage1_kernel<<<GRID_S1, 256, 0, stream>>>(pvq, paq, pvk, pak, av, va,
                                               spu_a, spu_v, av_ids, va_ids,
                                               n_av, n_va, ws, out);
    prob2_kernel<<<GRID_PB, 256, 0, stream>>>(av_ids, va_ids, n_av, n_va,
                                              u_v, u_a, ws, out);
}